// Round 20
// baseline (302.621 us; speedup 1.0000x reference)
//
#include <hip/hip_runtime.h>
#include <math.h>

#define N_NODES 100000
#define N_EDGES 3200000
#define H 10
#define S 12          // f32 node-table stride (48B)
#define SU 8          // packed-u stride in uints (32B)
#define IN_DIM 16
#define WPT 8         // lanes per node in gather passes
#define NB 128        // nodes per bucket
#define NBKT 782      // ceil(N_NODES / NB)
#define BCAP 4608     // capacity/bucket (mean 4092, +8 sigma)
#define FTILE 4096    // edges per fill block (8 per thread @512)
#define NFB 782       // ceil(N_EDGES / FTILE)
#define NT1 512       // fill1 threads
#define ROWM 0x1FFFFu

struct ent12 { unsigned a, b, w; };   // {bf16(a0,a1), bf16(a2,a3), row | cl<<17}

// ============ bptr init ============
__global__ __launch_bounds__(256) void k_binit(int* __restrict__ bptr)
{
    int i = blockIdx.x * 256 + threadIdx.x;
    if (i < NBKT) bptr[i] = i * BCAP;
}

// ---- bf16 pack (round-to-nearest-even) / unpack ----
__device__ __forceinline__ unsigned pack2bf(float a, float b)
{
    unsigned ua = __float_as_uint(a), ub = __float_as_uint(b);
    unsigned ra = (ua + 0x7FFFu + ((ua >> 16) & 1u)) >> 16;
    unsigned rb = (ub + 0x7FFFu + ((ub >> 16) & 1u)) >> 16;
    return ra | (rb << 16);
}
__device__ __forceinline__ float bflo(unsigned v) { return __uint_as_float(v << 16); }
__device__ __forceinline__ float bfhi(unsigned v) { return __uint_as_float(v & 0xffff0000u); }

// ============ fill phase 1: LDS-sorted tile scatter -> BURST writes (12B recs) ============
__global__ __launch_bounds__(NT1) void k_fill1(const int* __restrict__ ei,
    const float* __restrict__ attr, int* __restrict__ bptr,
    ent12* __restrict__ stage)
{
    __shared__ int lcnt[NBKT];
    __shared__ int lbase[NBKT];
    __shared__ int lscan[NBKT];
    __shared__ int sscan[2][NT1];
    __shared__ unsigned sa[FTILE], sb[FTILE], srw[FTILE];
    __shared__ unsigned short sbkt[FTILE];
    int tid = threadIdx.x;
    int base = blockIdx.x * FTILE;
    for (int k = tid; k < NBKT; k += NT1) lcnt[k] = 0;
    __syncthreads();
    // phase A: histogram
    int c[FTILE / NT1];
    #pragma unroll
    for (int k = 0; k < FTILE / NT1; ++k) {
        int e = base + k * NT1 + tid;
        c[k] = (e < N_EDGES) ? ei[N_EDGES + e] : -1;
        if (c[k] >= 0) atomicAdd(&lcnt[c[k] >> 7], 1);
    }
    __syncthreads();
    // phase B: exclusive scan of bucket counts (2 buckets/thread)
    int b0 = 2 * tid, b1 = 2 * tid + 1;
    int v0 = (b0 < NBKT) ? lcnt[b0] : 0;
    int v1 = (b1 < NBKT) ? lcnt[b1] : 0;
    int psum = v0 + v1;
    sscan[0][tid] = psum;
    __syncthreads();
    int cur = 0;
    for (int off = 1; off < NT1; off <<= 1) {
        int t = (tid >= off) ? sscan[cur][tid - off] : 0;
        int xx = sscan[cur][tid] + t;
        sscan[cur ^ 1][tid] = xx;
        cur ^= 1;
        __syncthreads();
    }
    int ep = sscan[cur][tid] - psum;
    if (b0 < NBKT) lscan[b0] = ep;
    if (b1 < NBKT) lscan[b1] = ep + v0;
    __syncthreads();
    // phase C: reserve global runs (exact size) + reset counters
    for (int k = tid; k < NBKT; k += NT1) {
        int n = lcnt[k];
        lbase[k] = n ? atomicAdd(&bptr[k], n) : 0;
        lcnt[k] = 0;
    }
    __syncthreads();
    // phase D: stage into LDS ordered by bucket
    #pragma unroll
    for (int k = 0; k < FTILE / NT1; ++k) {
        if (c[k] < 0) continue;
        int e = base + k * NT1 + tid;
        int b = c[k] >> 7;
        int slot = atomicAdd(&lcnt[b], 1);
        int pos = lscan[b] + slot;
        float4 a = ((const float4*)attr)[e];
        sa[pos] = pack2bf(a.x, a.y);
        sb[pos] = pack2bf(a.z, a.w);
        srw[pos] = (unsigned)ei[e] | ((unsigned)(c[k] & (NB - 1)) << 17);
        sbkt[pos] = (unsigned short)b;
    }
    __syncthreads();
    // phase E: burst write — consecutive threads -> consecutive global dests
    int total = min(FTILE, N_EDGES - base);
    for (int i = tid; i < total; i += NT1) {
        int b = (int)sbkt[i];
        int dest = i - lscan[b] + lbase[b];
        if (dest < (b + 1) * BCAP) {
            ent12 v;
            v.a = sa[i];
            v.b = sb[i];
            v.w = srw[i];
            stage[dest] = v;
        }
    }
}

// ============ fill phase 2: per-bucket exact-CSR reorder + emit start/cnt ============
__global__ __launch_bounds__(256) void k_fill2(const ent12* __restrict__ stage,
    const int* __restrict__ bptr, ent12* __restrict__ entries,
    int* __restrict__ start, int* __restrict__ cnt)
{
    __shared__ int hist[NB];
    __shared__ int buf[2][NB];
    __shared__ int cur[NB];
    int tid = threadIdx.x;
    int b = blockIdx.x;
    if (tid < NB) hist[tid] = 0;
    __syncthreads();
    int st = b * BCAP;
    int en = min(bptr[b], st + BCAP);
    for (int e = st + tid; e < en; e += 256)
        atomicAdd(&hist[stage[e].w >> 17], 1);
    __syncthreads();
    if (tid < NB) buf[0][tid] = hist[tid];
    __syncthreads();
    int cs = 0;
    for (int off = 1; off < NB; off <<= 1) {
        if (tid < NB) {
            int t = (tid >= off) ? buf[cs][tid - off] : 0;
            buf[cs ^ 1][tid] = buf[cs][tid] + t;
        }
        cs ^= 1;
        __syncthreads();
    }
    if (tid < NB) {
        int ex = buf[cs][tid] - hist[tid];            // exclusive prefix
        cur[tid] = ex;
        int node = b * NB + tid;
        if (node < N_NODES) {
            start[node] = st + ex;
            cnt[node]   = hist[tid];
        }
    }
    __syncthreads();
    for (int e = st + tid; e < en; e += 256) {
        ent12 ent = stage[e];
        int cl = (int)(ent.w >> 17);
        int slot = st + atomicAdd(&cur[cl], 1);
        entries[slot] = ent;                          // confined to ~54KB window
    }
}

// ============ shared helper: ew from packed attr ============
__device__ __forceinline__ void ew_from_packed(unsigned px, unsigned py,
    const float* sW1, const float* sW2, float ew[H])
{
    float ax = bflo(px), ay = bfhi(px);
    float az = bflo(py), aw = bfhi(py);
    float tt[H];
    #pragma unroll
    for (int j = 0; j < H; ++j)
        tt[j] = fmaxf(fmaf(ax, sW1[j], fmaf(ay, sW1[H+j],
                      fmaf(az, sW1[2*H+j], aw*sW1[3*H+j]))), 0.f);
    #pragma unroll
    for (int ch = 0; ch < H; ++ch) {
        float v = 0.f;
        #pragma unroll
        for (int j = 0; j < H; ++j) v = fmaf(tt[j], sW2[j*H + ch], v);
        ew[ch] = fmaxf(v, 0.f);
    }
}

// ============ deg pass (fused node init), WPT lanes/node ============
__global__ __launch_bounds__(256) void k_deg(const ent12* __restrict__ entries,
    const int* __restrict__ start, const int* __restrict__ cnt,
    const float* __restrict__ W1, const float* __restrict__ W2,
    const float* __restrict__ x, const float* __restrict__ iW,
    const float* __restrict__ ib, const float* __restrict__ gw0,
    float* __restrict__ x_, float* __restrict__ dinv, unsigned* __restrict__ u)
{
    __shared__ float sW1[4*H], sW2[H*H], siW[IN_DIM*H], sib[H], sgw[H];
    int tid = threadIdx.x;
    for (int k = tid; k < 4*H; k += 256) sW1[k] = W1[k];
    for (int k = tid; k < H*H; k += 256) sW2[k] = W2[k];
    for (int k = tid; k < IN_DIM*H; k += 256) siW[k] = iW[k];
    if (tid < H) sib[tid] = ib[tid];
    if (tid >= 32 && tid < 32+H) sgw[tid-32] = gw0[tid-32];
    __syncthreads();
    int node = blockIdx.x * (256 / WPT) + (tid >> 3);
    int r = tid & (WPT - 1);
    if (node >= N_NODES) return;
    int st = start[node], n = cnt[node];
    float s[H];
    #pragma unroll
    for (int ch = 0; ch < H; ++ch) s[ch] = 0.f;
    for (int e = st + r; e < st + n; e += WPT) {
        ent12 ent = entries[e];
        float ew[H];
        ew_from_packed(ent.a, ent.b, sW1, sW2, ew);
        #pragma unroll
        for (int ch = 0; ch < H; ++ch) s[ch] += ew[ch];
    }
    #pragma unroll
    for (int ch = 0; ch < H; ++ch) {
        s[ch] += __shfl_xor(s[ch], 1);
        s[ch] += __shfl_xor(s[ch], 2);
        s[ch] += __shfl_xor(s[ch], 4);
    }
    const float4* xv = (const float4*)(x + (size_t)node * IN_DIM);
    float xi[IN_DIM];
    float4 a0 = xv[0], a1 = xv[1], a2 = xv[2], a3 = xv[3];
    xi[0]=a0.x; xi[1]=a0.y; xi[2]=a0.z; xi[3]=a0.w;
    xi[4]=a1.x; xi[5]=a1.y; xi[6]=a1.z; xi[7]=a1.w;
    xi[8]=a2.x; xi[9]=a2.y; xi[10]=a2.z; xi[11]=a2.w;
    xi[12]=a3.x; xi[13]=a3.y; xi[14]=a3.z; xi[15]=a3.w;
    float xb[H], dv[H], uu[H];
    #pragma unroll
    for (int j = 0; j < H; ++j) {
        float a = sib[j];
        #pragma unroll
        for (int k = 0; k < IN_DIM; ++k) a = fmaf(xi[k], siW[k*H + j], a);
        xb[j] = a;
    }
    #pragma unroll
    for (int ch = 0; ch < H; ++ch) {
        float di = rsqrtf(1.0f + s[ch]);   // deg >= 1 (self loop)
        dv[ch] = di;
        uu[ch] = di * fmaxf(xb[ch], 0.f) * sgw[ch];
    }
    float* xd = x_   + (size_t)node * S;
    float* dd = dinv + (size_t)node * S;
    unsigned* ud = u + (size_t)node * SU;
    if (r == 0) {
        *(float4*)(xd+0) = make_float4(xb[0],xb[1],xb[2],xb[3]);
        *(float4*)(dd+0) = make_float4(dv[0],dv[1],dv[2],dv[3]);
        *(uint4*)(ud)    = make_uint4(pack2bf(uu[0],uu[1]), pack2bf(uu[2],uu[3]),
                                      pack2bf(uu[4],uu[5]), pack2bf(uu[6],uu[7]));
    } else if (r == 1) {
        *(float4*)(xd+4) = make_float4(xb[4],xb[5],xb[6],xb[7]);
        *(float4*)(dd+4) = make_float4(dv[4],dv[5],dv[6],dv[7]);
        ud[4] = pack2bf(uu[8], uu[9]);
    } else if (r == 2) {
        *(float4*)(xd+8) = make_float4(xb[8],xb[9],0.f,0.f);
        *(float4*)(dd+8) = make_float4(dv[8],dv[9],0.f,0.f);
    }
}

// ============ fused layer, WPT lanes/node, packed-u gather ============
template<int LAST>
__global__ __launch_bounds__(256) void k_layer(const ent12* __restrict__ entries,
    const int* __restrict__ start, const int* __restrict__ cnt,
    const float* __restrict__ W1, const float* __restrict__ W2,
    const float* __restrict__ x_, const float* __restrict__ dinv,
    const unsigned* __restrict__ uin,
    const float* __restrict__ lin, const float* __restrict__ gw_next,
    const float* __restrict__ gb, const float* __restrict__ oW,
    unsigned* __restrict__ uout, float* __restrict__ out)
{
    __shared__ float sW1[4*H], sW2[H*H], slin[2*H*H], sgw[H], sgb[H], soW[4*H];
    int tid = threadIdx.x;
    for (int k = tid; k < 4*H; k += 256) sW1[k] = W1[k];
    for (int k = tid; k < H*H; k += 256) sW2[k] = W2[k];
    for (int k = tid; k < 2*H*H; k += 256) slin[k] = lin[k];
    if (tid < H) sgb[tid] = gb[tid];
    if (LAST) { if (tid < 4*H) soW[tid] = oW[tid]; }
    else      { if (tid >= 64 && tid < 64+H) sgw[tid-64] = gw_next[tid-64]; }
    __syncthreads();
    int node = blockIdx.x * (256 / WPT) + (tid >> 3);
    int r = tid & (WPT - 1);
    if (node >= N_NODES) return;
    int st = start[node], n = cnt[node];
    float s[H];
    #pragma unroll
    for (int ch = 0; ch < H; ++ch) s[ch] = 0.f;
    for (int e = st + r; e < st + n; e += WPT) {
        ent12 ent = entries[e];
        float ew[H];
        ew_from_packed(ent.a, ent.b, sW1, sW2, ew);
        const unsigned* up = uin + (size_t)(ent.w & ROWM) * SU;
        uint4 w = *(const uint4*)up;
        unsigned w2 = up[4];
        float ur[H];
        ur[0]=bflo(w.x); ur[1]=bfhi(w.x);
        ur[2]=bflo(w.y); ur[3]=bfhi(w.y);
        ur[4]=bflo(w.z); ur[5]=bfhi(w.z);
        ur[6]=bflo(w.w); ur[7]=bfhi(w.w);
        ur[8]=bflo(w2);  ur[9]=bfhi(w2);
        #pragma unroll
        for (int ch = 0; ch < H; ++ch) s[ch] = fmaf(ew[ch], ur[ch], s[ch]);
    }
    #pragma unroll
    for (int ch = 0; ch < H; ++ch) {
        s[ch] += __shfl_xor(s[ch], 1);
        s[ch] += __shfl_xor(s[ch], 2);
        s[ch] += __shfl_xor(s[ch], 4);
    }
    const float* xi = x_   + (size_t)node * S;
    const float* di = dinv + (size_t)node * S;
    const unsigned* us = uin + (size_t)node * SU;
    uint4 wv = *(const uint4*)us;
    unsigned wv2 = us[4];
    float ui[H];
    ui[0]=bflo(wv.x); ui[1]=bfhi(wv.x);
    ui[2]=bflo(wv.y); ui[3]=bfhi(wv.y);
    ui[4]=bflo(wv.z); ui[5]=bfhi(wv.z);
    ui[6]=bflo(wv.w); ui[7]=bfhi(wv.w);
    ui[8]=bflo(wv2);  ui[9]=bfhi(wv2);
    float xv[H], agg[H];
    #pragma unroll
    for (int ch = 0; ch < H; ++ch) {
        xv[ch] = xi[ch];
        agg[ch] = di[ch] * (s[ch] + ui[ch]) + sgb[ch];  // self-loop folded in
    }
    float h[H];
    #pragma unroll
    for (int j = 0; j < H; ++j) {
        float a = xv[j];                                 // residual
        #pragma unroll
        for (int k = 0; k < H; ++k) a = fmaf(xv[k], slin[k*H + j], a);
        #pragma unroll
        for (int k = 0; k < H; ++k) a = fmaf(agg[k], slin[(H+k)*H + j], a);
        h[j] = a;
    }
    if (!LAST) {
        float un[H];
        #pragma unroll
        for (int ch = 0; ch < H; ++ch)
            un[ch] = di[ch] * fmaxf(h[ch], 0.f) * sgw[ch];
        unsigned* ud = uout + (size_t)node * SU;
        if (r == 0)
            *(uint4*)ud = make_uint4(pack2bf(un[0],un[1]), pack2bf(un[2],un[3]),
                                     pack2bf(un[4],un[5]), pack2bf(un[6],un[7]));
        else if (r == 1)
            ud[4] = pack2bf(un[8], un[9]);
    } else {
        float z0 = 0.f, z1 = 0.f;
        #pragma unroll
        for (int k = 0; k < H; ++k) { z0 = fmaf(xv[k], soW[2*k],   z0);
                                      z1 = fmaf(xv[k], soW[2*k+1], z1); }
        #pragma unroll
        for (int k = 0; k < H; ++k) { float hr = fmaxf(h[k], 0.f);
                                      z0 = fmaf(hr, soW[2*(H+k)],   z0);
                                      z1 = fmaf(hr, soW[2*(H+k)+1], z1); }
        if (r == 0) out[node] = 1.0f / (1.0f + expf(z0 - z1));
    }
}

extern "C" void kernel_launch(void* const* d_in, const int* in_sizes, int n_in,
                              void* d_out, int out_size, void* d_ws, size_t ws_size,
                              hipStream_t stream)
{
    const float* x     = (const float*)d_in[0];
    const int*   ei    = (const int*)  d_in[1];
    const float* attr  = (const float*)d_in[2];
    const float* ew_W1 = (const float*)d_in[3];
    const float* ew_W2 = (const float*)d_in[4];
    const float* iW    = (const float*)d_in[5];
    const float* ib    = (const float*)d_in[6];
    const float* gcn_w = (const float*)d_in[7];
    const float* gcn_b = (const float*)d_in[8];
    const float* lin_W = (const float*)d_in[9];
    const float* oW    = (const float*)d_in[10];
    float* out = (float*)d_out;
    char* ws = (char*)d_ws;

    size_t o = 0;
    ent12* stage   = (ent12*)(ws + o); o += (size_t)NBKT * BCAP * 12;      // 43.2 MB
    ent12* entries = (ent12*)(ws + o); o += (size_t)NBKT * BCAP * 12;      // 43.2 MB
    float* x_   = (float*)(ws + o); o += (size_t)N_NODES * S * 4;          // 4.8 MB
    float* dinv = (float*)(ws + o); o += (size_t)N_NODES * S * 4;          // 4.8 MB
    unsigned* u_a = (unsigned*)(ws + o); o += (size_t)N_NODES * SU * 4;    // 3.2 MB
    unsigned* u_b = (unsigned*)(ws + o); o += (size_t)N_NODES * SU * 4;    // 3.2 MB
    int* cnt    = (int*)(ws + o); o += (size_t)N_NODES * 4;
    int* start  = (int*)(ws + o); o += (size_t)N_NODES * 4;
    int* bptr   = (int*)(ws + o); o += (size_t)NBKT * 4;

    dim3 blk(256);
    dim3 ggrid((N_NODES * WPT + 255) / 256);   // 3125 blocks, 32 nodes each

    k_binit<<<(NBKT + 255) / 256, blk, 0, stream>>>(bptr);
    k_fill1<<<NFB, NT1, 0, stream>>>(ei, attr, bptr, stage);
    k_fill2<<<NBKT, blk, 0, stream>>>(stage, bptr, entries, start, cnt);

    k_deg  <<<ggrid, blk, 0, stream>>>(entries, start, cnt, ew_W1, ew_W2,
                                       x, iW, ib, gcn_w, x_, dinv, u_a);
    // layer 0: reads u_a, writes u_b
    k_layer<0><<<ggrid, blk, 0, stream>>>(entries, start, cnt, ew_W1, ew_W2,
        x_, dinv, u_a, lin_W + 0*2*H*H, gcn_w + 1*H, gcn_b + 0*H, oW, u_b, out);
    // layer 1: reads u_b, writes u_a
    k_layer<0><<<ggrid, blk, 0, stream>>>(entries, start, cnt, ew_W1, ew_W2,
        x_, dinv, u_b, lin_W + 1*2*H*H, gcn_w + 2*H, gcn_b + 1*H, oW, u_a, out);
    // layer 2: reads u_a, writes out
    k_layer<1><<<ggrid, blk, 0, stream>>>(entries, start, cnt, ew_W1, ew_W2,
        x_, dinv, u_a, lin_W + 2*2*H*H, nullptr, gcn_b + 2*H, oW, nullptr, out);
}

// Round 21
// 282.119 us; speedup vs baseline: 1.0727x; 1.0727x over previous
//
#include <hip/hip_runtime.h>
#include <math.h>

#define N_NODES 100000
#define N_EDGES 3200000
#define H 10
#define S 12          // f32 node-table stride (48B)
#define SU 8          // packed-u stride in uints (32B)
#define IN_DIM 16
#define WPT 4         // lanes per node in gather passes (4: halves epilogue redundancy)
#define NB 128        // nodes per bucket
#define NBKT 782      // ceil(N_NODES / NB)
#define BCAP 4608     // capacity/bucket (mean 4092, +8 sigma)
#define FTILE 4096    // edges per fill block (8 per thread @512)
#define NFB 782       // ceil(N_EDGES / FTILE)
#define NT1 512       // fill1 threads
#define ROWM 0x1FFFFu

struct ent12 { unsigned a, b, w; };   // {bf16(a0,a1), bf16(a2,a3), row | cl<<17}

// ============ bptr init ============
__global__ __launch_bounds__(256) void k_binit(int* __restrict__ bptr)
{
    int i = blockIdx.x * 256 + threadIdx.x;
    if (i < NBKT) bptr[i] = i * BCAP;
}

// ---- bf16 pack (round-to-nearest-even) / unpack ----
__device__ __forceinline__ unsigned pack2bf(float a, float b)
{
    unsigned ua = __float_as_uint(a), ub = __float_as_uint(b);
    unsigned ra = (ua + 0x7FFFu + ((ua >> 16) & 1u)) >> 16;
    unsigned rb = (ub + 0x7FFFu + ((ub >> 16) & 1u)) >> 16;
    return ra | (rb << 16);
}
__device__ __forceinline__ float bflo(unsigned v) { return __uint_as_float(v << 16); }
__device__ __forceinline__ float bfhi(unsigned v) { return __uint_as_float(v & 0xffff0000u); }

// ============ fill phase 1: LDS-sorted tile scatter -> BURST writes (12B recs) ============
__global__ __launch_bounds__(NT1) void k_fill1(const int* __restrict__ ei,
    const float* __restrict__ attr, int* __restrict__ bptr,
    ent12* __restrict__ stage)
{
    __shared__ int lcnt[NBKT];
    __shared__ int lbase[NBKT];
    __shared__ int lscan[NBKT];
    __shared__ int sscan[2][NT1];
    __shared__ unsigned sa[FTILE], sb[FTILE], srw[FTILE];
    __shared__ unsigned short sbkt[FTILE];
    int tid = threadIdx.x;
    int base = blockIdx.x * FTILE;
    for (int k = tid; k < NBKT; k += NT1) lcnt[k] = 0;
    __syncthreads();
    // phase A: histogram
    int c[FTILE / NT1];
    #pragma unroll
    for (int k = 0; k < FTILE / NT1; ++k) {
        int e = base + k * NT1 + tid;
        c[k] = (e < N_EDGES) ? ei[N_EDGES + e] : -1;
        if (c[k] >= 0) atomicAdd(&lcnt[c[k] >> 7], 1);
    }
    __syncthreads();
    // phase B: exclusive scan of bucket counts (2 buckets/thread)
    int b0 = 2 * tid, b1 = 2 * tid + 1;
    int v0 = (b0 < NBKT) ? lcnt[b0] : 0;
    int v1 = (b1 < NBKT) ? lcnt[b1] : 0;
    int psum = v0 + v1;
    sscan[0][tid] = psum;
    __syncthreads();
    int cur = 0;
    for (int off = 1; off < NT1; off <<= 1) {
        int t = (tid >= off) ? sscan[cur][tid - off] : 0;
        int xx = sscan[cur][tid] + t;
        sscan[cur ^ 1][tid] = xx;
        cur ^= 1;
        __syncthreads();
    }
    int ep = sscan[cur][tid] - psum;
    if (b0 < NBKT) lscan[b0] = ep;
    if (b1 < NBKT) lscan[b1] = ep + v0;
    __syncthreads();
    // phase C: reserve global runs (exact size) + reset counters
    for (int k = tid; k < NBKT; k += NT1) {
        int n = lcnt[k];
        lbase[k] = n ? atomicAdd(&bptr[k], n) : 0;
        lcnt[k] = 0;
    }
    __syncthreads();
    // phase D: stage into LDS ordered by bucket
    #pragma unroll
    for (int k = 0; k < FTILE / NT1; ++k) {
        if (c[k] < 0) continue;
        int e = base + k * NT1 + tid;
        int b = c[k] >> 7;
        int slot = atomicAdd(&lcnt[b], 1);
        int pos = lscan[b] + slot;
        float4 a = ((const float4*)attr)[e];
        sa[pos] = pack2bf(a.x, a.y);
        sb[pos] = pack2bf(a.z, a.w);
        srw[pos] = (unsigned)ei[e] | ((unsigned)(c[k] & (NB - 1)) << 17);
        sbkt[pos] = (unsigned short)b;
    }
    __syncthreads();
    // phase E: burst write — consecutive threads -> consecutive global dests
    int total = min(FTILE, N_EDGES - base);
    for (int i = tid; i < total; i += NT1) {
        int b = (int)sbkt[i];
        int dest = i - lscan[b] + lbase[b];
        if (dest < (b + 1) * BCAP) {
            ent12 v;
            v.a = sa[i];
            v.b = sb[i];
            v.w = srw[i];
            stage[dest] = v;
        }
    }
}

// ============ fill phase 2: per-bucket exact-CSR reorder + emit start/cnt ============
__global__ __launch_bounds__(256) void k_fill2(const ent12* __restrict__ stage,
    const int* __restrict__ bptr, ent12* __restrict__ entries,
    int* __restrict__ start, int* __restrict__ cnt)
{
    __shared__ int hist[NB];
    __shared__ int buf[2][NB];
    __shared__ int cur[NB];
    int tid = threadIdx.x;
    int b = blockIdx.x;
    if (tid < NB) hist[tid] = 0;
    __syncthreads();
    int st = b * BCAP;
    int en = min(bptr[b], st + BCAP);
    for (int e = st + tid; e < en; e += 256)
        atomicAdd(&hist[stage[e].w >> 17], 1);
    __syncthreads();
    if (tid < NB) buf[0][tid] = hist[tid];
    __syncthreads();
    int cs = 0;
    for (int off = 1; off < NB; off <<= 1) {
        if (tid < NB) {
            int t = (tid >= off) ? buf[cs][tid - off] : 0;
            buf[cs ^ 1][tid] = buf[cs][tid] + t;
        }
        cs ^= 1;
        __syncthreads();
    }
    if (tid < NB) {
        int ex = buf[cs][tid] - hist[tid];            // exclusive prefix
        cur[tid] = ex;
        int node = b * NB + tid;
        if (node < N_NODES) {
            start[node] = st + ex;
            cnt[node]   = hist[tid];
        }
    }
    __syncthreads();
    for (int e = st + tid; e < en; e += 256) {
        ent12 ent = stage[e];
        int cl = (int)(ent.w >> 17);
        int slot = st + atomicAdd(&cur[cl], 1);
        entries[slot] = ent;                          // confined to ~54KB window
    }
}

// ============ shared helper: ew from packed attr ============
__device__ __forceinline__ void ew_from_packed(unsigned px, unsigned py,
    const float* sW1, const float* sW2, float ew[H])
{
    float ax = bflo(px), ay = bfhi(px);
    float az = bflo(py), aw = bfhi(py);
    float tt[H];
    #pragma unroll
    for (int j = 0; j < H; ++j)
        tt[j] = fmaxf(fmaf(ax, sW1[j], fmaf(ay, sW1[H+j],
                      fmaf(az, sW1[2*H+j], aw*sW1[3*H+j]))), 0.f);
    #pragma unroll
    for (int ch = 0; ch < H; ++ch) {
        float v = 0.f;
        #pragma unroll
        for (int j = 0; j < H; ++j) v = fmaf(tt[j], sW2[j*H + ch], v);
        ew[ch] = fmaxf(v, 0.f);
    }
}

// ============ deg pass (fused node init), WPT lanes/node ============
__global__ __launch_bounds__(256) void k_deg(const ent12* __restrict__ entries,
    const int* __restrict__ start, const int* __restrict__ cnt,
    const float* __restrict__ W1, const float* __restrict__ W2,
    const float* __restrict__ x, const float* __restrict__ iW,
    const float* __restrict__ ib, const float* __restrict__ gw0,
    float* __restrict__ x_, float* __restrict__ dinv, unsigned* __restrict__ u)
{
    __shared__ float sW1[4*H], sW2[H*H], siW[IN_DIM*H], sib[H], sgw[H];
    int tid = threadIdx.x;
    for (int k = tid; k < 4*H; k += 256) sW1[k] = W1[k];
    for (int k = tid; k < H*H; k += 256) sW2[k] = W2[k];
    for (int k = tid; k < IN_DIM*H; k += 256) siW[k] = iW[k];
    if (tid < H) sib[tid] = ib[tid];
    if (tid >= 32 && tid < 32+H) sgw[tid-32] = gw0[tid-32];
    __syncthreads();
    int node = blockIdx.x * (256 / WPT) + (tid >> 2);
    int r = tid & (WPT - 1);
    if (node >= N_NODES) return;
    int st = start[node], n = cnt[node];
    float s[H];
    #pragma unroll
    for (int ch = 0; ch < H; ++ch) s[ch] = 0.f;
    for (int e = st + r; e < st + n; e += WPT) {
        ent12 ent = entries[e];
        float ew[H];
        ew_from_packed(ent.a, ent.b, sW1, sW2, ew);
        #pragma unroll
        for (int ch = 0; ch < H; ++ch) s[ch] += ew[ch];
    }
    #pragma unroll
    for (int ch = 0; ch < H; ++ch) {
        s[ch] += __shfl_xor(s[ch], 1);
        s[ch] += __shfl_xor(s[ch], 2);
    }
    const float4* xv = (const float4*)(x + (size_t)node * IN_DIM);
    float xi[IN_DIM];
    float4 a0 = xv[0], a1 = xv[1], a2 = xv[2], a3 = xv[3];
    xi[0]=a0.x; xi[1]=a0.y; xi[2]=a0.z; xi[3]=a0.w;
    xi[4]=a1.x; xi[5]=a1.y; xi[6]=a1.z; xi[7]=a1.w;
    xi[8]=a2.x; xi[9]=a2.y; xi[10]=a2.z; xi[11]=a2.w;
    xi[12]=a3.x; xi[13]=a3.y; xi[14]=a3.z; xi[15]=a3.w;
    float xb[H], dv[H], uu[H];
    #pragma unroll
    for (int j = 0; j < H; ++j) {
        float a = sib[j];
        #pragma unroll
        for (int k = 0; k < IN_DIM; ++k) a = fmaf(xi[k], siW[k*H + j], a);
        xb[j] = a;
    }
    #pragma unroll
    for (int ch = 0; ch < H; ++ch) {
        float di = rsqrtf(1.0f + s[ch]);   // deg >= 1 (self loop)
        dv[ch] = di;
        uu[ch] = di * fmaxf(xb[ch], 0.f) * sgw[ch];
    }
    float* xd = x_   + (size_t)node * S;
    float* dd = dinv + (size_t)node * S;
    unsigned* ud = u + (size_t)node * SU;
    if (r == 0) {
        *(float4*)(xd+0) = make_float4(xb[0],xb[1],xb[2],xb[3]);
        *(float4*)(dd+0) = make_float4(dv[0],dv[1],dv[2],dv[3]);
        *(uint4*)(ud)    = make_uint4(pack2bf(uu[0],uu[1]), pack2bf(uu[2],uu[3]),
                                      pack2bf(uu[4],uu[5]), pack2bf(uu[6],uu[7]));
    } else if (r == 1) {
        *(float4*)(xd+4) = make_float4(xb[4],xb[5],xb[6],xb[7]);
        *(float4*)(dd+4) = make_float4(dv[4],dv[5],dv[6],dv[7]);
        ud[4] = pack2bf(uu[8], uu[9]);
    } else if (r == 2) {
        *(float4*)(xd+8) = make_float4(xb[8],xb[9],0.f,0.f);
        *(float4*)(dd+8) = make_float4(dv[8],dv[9],0.f,0.f);
    }
}

// ============ fused layer, WPT lanes/node, packed-u gather ============
template<int LAST>
__global__ __launch_bounds__(256) void k_layer(const ent12* __restrict__ entries,
    const int* __restrict__ start, const int* __restrict__ cnt,
    const float* __restrict__ W1, const float* __restrict__ W2,
    const float* __restrict__ x_, const float* __restrict__ dinv,
    const unsigned* __restrict__ uin,
    const float* __restrict__ lin, const float* __restrict__ gw_next,
    const float* __restrict__ gb, const float* __restrict__ oW,
    unsigned* __restrict__ uout, float* __restrict__ out)
{
    __shared__ float sW1[4*H], sW2[H*H], slin[2*H*H], sgw[H], sgb[H], soW[4*H];
    int tid = threadIdx.x;
    for (int k = tid; k < 4*H; k += 256) sW1[k] = W1[k];
    for (int k = tid; k < H*H; k += 256) sW2[k] = W2[k];
    for (int k = tid; k < 2*H*H; k += 256) slin[k] = lin[k];
    if (tid < H) sgb[tid] = gb[tid];
    if (LAST) { if (tid < 4*H) soW[tid] = oW[tid]; }
    else      { if (tid >= 64 && tid < 64+H) sgw[tid-64] = gw_next[tid-64]; }
    __syncthreads();
    int node = blockIdx.x * (256 / WPT) + (tid >> 2);
    int r = tid & (WPT - 1);
    if (node >= N_NODES) return;
    int st = start[node], n = cnt[node];
    float s[H];
    #pragma unroll
    for (int ch = 0; ch < H; ++ch) s[ch] = 0.f;
    for (int e = st + r; e < st + n; e += WPT) {
        ent12 ent = entries[e];
        float ew[H];
        ew_from_packed(ent.a, ent.b, sW1, sW2, ew);
        const unsigned* up = uin + (size_t)(ent.w & ROWM) * SU;
        uint4 w = *(const uint4*)up;
        unsigned w2 = up[4];
        float ur[H];
        ur[0]=bflo(w.x); ur[1]=bfhi(w.x);
        ur[2]=bflo(w.y); ur[3]=bfhi(w.y);
        ur[4]=bflo(w.z); ur[5]=bfhi(w.z);
        ur[6]=bflo(w.w); ur[7]=bfhi(w.w);
        ur[8]=bflo(w2);  ur[9]=bfhi(w2);
        #pragma unroll
        for (int ch = 0; ch < H; ++ch) s[ch] = fmaf(ew[ch], ur[ch], s[ch]);
    }
    #pragma unroll
    for (int ch = 0; ch < H; ++ch) {
        s[ch] += __shfl_xor(s[ch], 1);
        s[ch] += __shfl_xor(s[ch], 2);
    }
    const float* xi = x_   + (size_t)node * S;
    const float* di = dinv + (size_t)node * S;
    const unsigned* us = uin + (size_t)node * SU;
    uint4 wv = *(const uint4*)us;
    unsigned wv2 = us[4];
    float ui[H];
    ui[0]=bflo(wv.x); ui[1]=bfhi(wv.x);
    ui[2]=bflo(wv.y); ui[3]=bfhi(wv.y);
    ui[4]=bflo(wv.z); ui[5]=bfhi(wv.z);
    ui[6]=bflo(wv.w); ui[7]=bfhi(wv.w);
    ui[8]=bflo(wv2);  ui[9]=bfhi(wv2);
    float xv[H], agg[H];
    #pragma unroll
    for (int ch = 0; ch < H; ++ch) {
        xv[ch] = xi[ch];
        agg[ch] = di[ch] * (s[ch] + ui[ch]) + sgb[ch];  // self-loop folded in
    }
    float h[H];
    #pragma unroll
    for (int j = 0; j < H; ++j) {
        float a = xv[j];                                 // residual
        #pragma unroll
        for (int k = 0; k < H; ++k) a = fmaf(xv[k], slin[k*H + j], a);
        #pragma unroll
        for (int k = 0; k < H; ++k) a = fmaf(agg[k], slin[(H+k)*H + j], a);
        h[j] = a;
    }
    if (!LAST) {
        float un[H];
        #pragma unroll
        for (int ch = 0; ch < H; ++ch)
            un[ch] = di[ch] * fmaxf(h[ch], 0.f) * sgw[ch];
        unsigned* ud = uout + (size_t)node * SU;
        if (r == 0)
            *(uint4*)ud = make_uint4(pack2bf(un[0],un[1]), pack2bf(un[2],un[3]),
                                     pack2bf(un[4],un[5]), pack2bf(un[6],un[7]));
        else if (r == 1)
            ud[4] = pack2bf(un[8], un[9]);
    } else {
        float z0 = 0.f, z1 = 0.f;
        #pragma unroll
        for (int k = 0; k < H; ++k) { z0 = fmaf(xv[k], soW[2*k],   z0);
                                      z1 = fmaf(xv[k], soW[2*k+1], z1); }
        #pragma unroll
        for (int k = 0; k < H; ++k) { float hr = fmaxf(h[k], 0.f);
                                      z0 = fmaf(hr, soW[2*(H+k)],   z0);
                                      z1 = fmaf(hr, soW[2*(H+k)+1], z1); }
        if (r == 0) out[node] = 1.0f / (1.0f + expf(z0 - z1));
    }
}

extern "C" void kernel_launch(void* const* d_in, const int* in_sizes, int n_in,
                              void* d_out, int out_size, void* d_ws, size_t ws_size,
                              hipStream_t stream)
{
    const float* x     = (const float*)d_in[0];
    const int*   ei    = (const int*)  d_in[1];
    const float* attr  = (const float*)d_in[2];
    const float* ew_W1 = (const float*)d_in[3];
    const float* ew_W2 = (const float*)d_in[4];
    const float* iW    = (const float*)d_in[5];
    const float* ib    = (const float*)d_in[6];
    const float* gcn_w = (const float*)d_in[7];
    const float* gcn_b = (const float*)d_in[8];
    const float* lin_W = (const float*)d_in[9];
    const float* oW    = (const float*)d_in[10];
    float* out = (float*)d_out;
    char* ws = (char*)d_ws;

    size_t o = 0;
    ent12* stage   = (ent12*)(ws + o); o += (size_t)NBKT * BCAP * 12;      // 43.2 MB
    ent12* entries = (ent12*)(ws + o); o += (size_t)NBKT * BCAP * 12;      // 43.2 MB
    float* x_   = (float*)(ws + o); o += (size_t)N_NODES * S * 4;          // 4.8 MB
    float* dinv = (float*)(ws + o); o += (size_t)N_NODES * S * 4;          // 4.8 MB
    unsigned* u_a = (unsigned*)(ws + o); o += (size_t)N_NODES * SU * 4;    // 3.2 MB
    unsigned* u_b = (unsigned*)(ws + o); o += (size_t)N_NODES * SU * 4;    // 3.2 MB
    int* cnt    = (int*)(ws + o); o += (size_t)N_NODES * 4;
    int* start  = (int*)(ws + o); o += (size_t)N_NODES * 4;
    int* bptr   = (int*)(ws + o); o += (size_t)NBKT * 4;

    dim3 blk(256);
    dim3 ggrid((N_NODES * WPT + 255) / 256);   // 1563 blocks, 64 nodes each

    k_binit<<<(NBKT + 255) / 256, blk, 0, stream>>>(bptr);
    k_fill1<<<NFB, NT1, 0, stream>>>(ei, attr, bptr, stage);
    k_fill2<<<NBKT, blk, 0, stream>>>(stage, bptr, entries, start, cnt);

    k_deg  <<<ggrid, blk, 0, stream>>>(entries, start, cnt, ew_W1, ew_W2,
                                       x, iW, ib, gcn_w, x_, dinv, u_a);
    // layer 0: reads u_a, writes u_b
    k_layer<0><<<ggrid, blk, 0, stream>>>(entries, start, cnt, ew_W1, ew_W2,
        x_, dinv, u_a, lin_W + 0*2*H*H, gcn_w + 1*H, gcn_b + 0*H, oW, u_b, out);
    // layer 1: reads u_b, writes u_a
    k_layer<0><<<ggrid, blk, 0, stream>>>(entries, start, cnt, ew_W1, ew_W2,
        x_, dinv, u_b, lin_W + 1*2*H*H, gcn_w + 2*H, gcn_b + 1*H, oW, u_a, out);
    // layer 2: reads u_a, writes out
    k_layer<1><<<ggrid, blk, 0, stream>>>(entries, start, cnt, ew_W1, ew_W2,
        x_, dinv, u_a, lin_W + 2*2*H*H, nullptr, gcn_b + 2*H, oW, nullptr, out);
}

// Round 22
// 272.453 us; speedup vs baseline: 1.1107x; 1.0355x over previous
//
#include <hip/hip_runtime.h>
#include <math.h>

#define N_NODES 100000
#define N_EDGES 3200000
#define H 10
#define S 12          // f32 node-table stride (48B)
#define SU 8          // packed-u stride in uints (32B)
#define IN_DIM 16
#define WPT 4         // lanes per node in gather passes
#define NB 128        // nodes per bucket
#define NBKT 782      // ceil(N_NODES / NB)
#define BCAP 4608     // capacity/bucket (mean 4092, +8 sigma)
#define FTILE 4096    // edges per fill block (4 per thread @1024)
#define NFB 782       // ceil(N_EDGES / FTILE)
#define NT1 1024      // fill1 threads
#define NT2 512       // fill2 threads
#define ROWM 0x1FFFFu

struct ent12 { unsigned a, b, w; };   // {bf16(a0,a1), bf16(a2,a3), row | cl<<17}

// ============ bptr init ============
__global__ __launch_bounds__(256) void k_binit(int* __restrict__ bptr)
{
    int i = blockIdx.x * 256 + threadIdx.x;
    if (i < NBKT) bptr[i] = i * BCAP;
}

// ---- bf16 pack (round-to-nearest-even) / unpack ----
__device__ __forceinline__ unsigned pack2bf(float a, float b)
{
    unsigned ua = __float_as_uint(a), ub = __float_as_uint(b);
    unsigned ra = (ua + 0x7FFFu + ((ua >> 16) & 1u)) >> 16;
    unsigned rb = (ub + 0x7FFFu + ((ub >> 16) & 1u)) >> 16;
    return ra | (rb << 16);
}
__device__ __forceinline__ float bflo(unsigned v) { return __uint_as_float(v << 16); }
__device__ __forceinline__ float bfhi(unsigned v) { return __uint_as_float(v & 0xffff0000u); }

// ============ fill phase 1: LDS-sorted tile scatter -> BURST writes (12B recs) ============
__global__ __launch_bounds__(NT1) void k_fill1(const int* __restrict__ ei,
    const float* __restrict__ attr, int* __restrict__ bptr,
    ent12* __restrict__ stage)
{
    __shared__ int lcnt[NBKT];
    __shared__ int lbase[NBKT];
    __shared__ int lscan[NBKT];
    __shared__ int sscan[2][NT1];
    __shared__ unsigned sa[FTILE], sb[FTILE], srw[FTILE];
    __shared__ unsigned short sbkt[FTILE];
    int tid = threadIdx.x;
    int base = blockIdx.x * FTILE;
    for (int k = tid; k < NBKT; k += NT1) lcnt[k] = 0;
    __syncthreads();
    // phase A: histogram
    int c[FTILE / NT1];
    #pragma unroll
    for (int k = 0; k < FTILE / NT1; ++k) {
        int e = base + k * NT1 + tid;
        c[k] = (e < N_EDGES) ? ei[N_EDGES + e] : -1;
        if (c[k] >= 0) atomicAdd(&lcnt[c[k] >> 7], 1);
    }
    __syncthreads();
    // phase B: exclusive scan of bucket counts (2 buckets/thread)
    int b0 = 2 * tid, b1 = 2 * tid + 1;
    int v0 = (b0 < NBKT) ? lcnt[b0] : 0;
    int v1 = (b1 < NBKT) ? lcnt[b1] : 0;
    int psum = v0 + v1;
    sscan[0][tid] = psum;
    __syncthreads();
    int cur = 0;
    for (int off = 1; off < NT1; off <<= 1) {
        int t = (tid >= off) ? sscan[cur][tid - off] : 0;
        int xx = sscan[cur][tid] + t;
        sscan[cur ^ 1][tid] = xx;
        cur ^= 1;
        __syncthreads();
    }
    int ep = sscan[cur][tid] - psum;
    if (b0 < NBKT) lscan[b0] = ep;
    if (b1 < NBKT) lscan[b1] = ep + v0;
    __syncthreads();
    // phase C: reserve global runs (exact size) + reset counters
    for (int k = tid; k < NBKT; k += NT1) {
        int n = lcnt[k];
        lbase[k] = n ? atomicAdd(&bptr[k], n) : 0;
        lcnt[k] = 0;
    }
    __syncthreads();
    // phase D: stage into LDS ordered by bucket
    #pragma unroll
    for (int k = 0; k < FTILE / NT1; ++k) {
        if (c[k] < 0) continue;
        int e = base + k * NT1 + tid;
        int b = c[k] >> 7;
        int slot = atomicAdd(&lcnt[b], 1);
        int pos = lscan[b] + slot;
        float4 a = ((const float4*)attr)[e];
        sa[pos] = pack2bf(a.x, a.y);
        sb[pos] = pack2bf(a.z, a.w);
        srw[pos] = (unsigned)ei[e] | ((unsigned)(c[k] & (NB - 1)) << 17);
        sbkt[pos] = (unsigned short)b;
    }
    __syncthreads();
    // phase E: burst write — consecutive threads -> consecutive global dests
    int total = min(FTILE, N_EDGES - base);
    for (int i = tid; i < total; i += NT1) {
        int b = (int)sbkt[i];
        int dest = i - lscan[b] + lbase[b];
        if (dest < (b + 1) * BCAP) {
            ent12 v;
            v.a = sa[i];
            v.b = sb[i];
            v.w = srw[i];
            stage[dest] = v;
        }
    }
}

// ============ fill phase 2: per-bucket exact-CSR reorder + emit start/cnt ============
__global__ __launch_bounds__(NT2) void k_fill2(const ent12* __restrict__ stage,
    const int* __restrict__ bptr, ent12* __restrict__ entries,
    int* __restrict__ start, int* __restrict__ cnt)
{
    __shared__ int hist[NB];
    __shared__ int buf[2][NB];
    __shared__ int cur[NB];
    int tid = threadIdx.x;
    int b = blockIdx.x;
    if (tid < NB) hist[tid] = 0;
    __syncthreads();
    int st = b * BCAP;
    int en = min(bptr[b], st + BCAP);
    for (int e = st + tid; e < en; e += NT2)
        atomicAdd(&hist[stage[e].w >> 17], 1);
    __syncthreads();
    if (tid < NB) buf[0][tid] = hist[tid];
    __syncthreads();
    int cs = 0;
    for (int off = 1; off < NB; off <<= 1) {
        if (tid < NB) {
            int t = (tid >= off) ? buf[cs][tid - off] : 0;
            buf[cs ^ 1][tid] = buf[cs][tid] + t;
        }
        cs ^= 1;
        __syncthreads();
    }
    if (tid < NB) {
        int ex = buf[cs][tid] - hist[tid];            // exclusive prefix
        cur[tid] = ex;
        int node = b * NB + tid;
        if (node < N_NODES) {
            start[node] = st + ex;
            cnt[node]   = hist[tid];
        }
    }
    __syncthreads();
    for (int e = st + tid; e < en; e += NT2) {
        ent12 ent = stage[e];
        int cl = (int)(ent.w >> 17);
        int slot = st + atomicAdd(&cur[cl], 1);
        entries[slot] = ent;                          // confined to ~54KB window
    }
}

// ============ shared helper: ew from packed attr ============
__device__ __forceinline__ void ew_from_packed(unsigned px, unsigned py,
    const float* sW1, const float* sW2, float ew[H])
{
    float ax = bflo(px), ay = bfhi(px);
    float az = bflo(py), aw = bfhi(py);
    float tt[H];
    #pragma unroll
    for (int j = 0; j < H; ++j)
        tt[j] = fmaxf(fmaf(ax, sW1[j], fmaf(ay, sW1[H+j],
                      fmaf(az, sW1[2*H+j], aw*sW1[3*H+j]))), 0.f);
    #pragma unroll
    for (int ch = 0; ch < H; ++ch) {
        float v = 0.f;
        #pragma unroll
        for (int j = 0; j < H; ++j) v = fmaf(tt[j], sW2[j*H + ch], v);
        ew[ch] = fmaxf(v, 0.f);
    }
}

// ============ deg pass (fused node init), WPT lanes/node ============
__global__ __launch_bounds__(256) void k_deg(const ent12* __restrict__ entries,
    const int* __restrict__ start, const int* __restrict__ cnt,
    const float* __restrict__ W1, const float* __restrict__ W2,
    const float* __restrict__ x, const float* __restrict__ iW,
    const float* __restrict__ ib, const float* __restrict__ gw0,
    float* __restrict__ x_, float* __restrict__ dinv, unsigned* __restrict__ u)
{
    __shared__ float sW1[4*H], sW2[H*H], siW[IN_DIM*H], sib[H], sgw[H];
    int tid = threadIdx.x;
    for (int k = tid; k < 4*H; k += 256) sW1[k] = W1[k];
    for (int k = tid; k < H*H; k += 256) sW2[k] = W2[k];
    for (int k = tid; k < IN_DIM*H; k += 256) siW[k] = iW[k];
    if (tid < H) sib[tid] = ib[tid];
    if (tid >= 32 && tid < 32+H) sgw[tid-32] = gw0[tid-32];
    __syncthreads();
    int node = blockIdx.x * (256 / WPT) + (tid >> 2);
    int r = tid & (WPT - 1);
    if (node >= N_NODES) return;
    int st = start[node], n = cnt[node];
    float s[H];
    #pragma unroll
    for (int ch = 0; ch < H; ++ch) s[ch] = 0.f;
    for (int e = st + r; e < st + n; e += WPT) {
        ent12 ent = entries[e];
        float ew[H];
        ew_from_packed(ent.a, ent.b, sW1, sW2, ew);
        #pragma unroll
        for (int ch = 0; ch < H; ++ch) s[ch] += ew[ch];
    }
    #pragma unroll
    for (int ch = 0; ch < H; ++ch) {
        s[ch] += __shfl_xor(s[ch], 1);
        s[ch] += __shfl_xor(s[ch], 2);
    }
    const float4* xv = (const float4*)(x + (size_t)node * IN_DIM);
    float xi[IN_DIM];
    float4 a0 = xv[0], a1 = xv[1], a2 = xv[2], a3 = xv[3];
    xi[0]=a0.x; xi[1]=a0.y; xi[2]=a0.z; xi[3]=a0.w;
    xi[4]=a1.x; xi[5]=a1.y; xi[6]=a1.z; xi[7]=a1.w;
    xi[8]=a2.x; xi[9]=a2.y; xi[10]=a2.z; xi[11]=a2.w;
    xi[12]=a3.x; xi[13]=a3.y; xi[14]=a3.z; xi[15]=a3.w;
    float xb[H], dv[H], uu[H];
    #pragma unroll
    for (int j = 0; j < H; ++j) {
        float a = sib[j];
        #pragma unroll
        for (int k = 0; k < IN_DIM; ++k) a = fmaf(xi[k], siW[k*H + j], a);
        xb[j] = a;
    }
    #pragma unroll
    for (int ch = 0; ch < H; ++ch) {
        float di = rsqrtf(1.0f + s[ch]);   // deg >= 1 (self loop)
        dv[ch] = di;
        uu[ch] = di * fmaxf(xb[ch], 0.f) * sgw[ch];
    }
    float* xd = x_   + (size_t)node * S;
    float* dd = dinv + (size_t)node * S;
    unsigned* ud = u + (size_t)node * SU;
    if (r == 0) {
        *(float4*)(xd+0) = make_float4(xb[0],xb[1],xb[2],xb[3]);
        *(float4*)(dd+0) = make_float4(dv[0],dv[1],dv[2],dv[3]);
        *(uint4*)(ud)    = make_uint4(pack2bf(uu[0],uu[1]), pack2bf(uu[2],uu[3]),
                                      pack2bf(uu[4],uu[5]), pack2bf(uu[6],uu[7]));
    } else if (r == 1) {
        *(float4*)(xd+4) = make_float4(xb[4],xb[5],xb[6],xb[7]);
        *(float4*)(dd+4) = make_float4(dv[4],dv[5],dv[6],dv[7]);
        ud[4] = pack2bf(uu[8], uu[9]);
    } else if (r == 2) {
        *(float4*)(xd+8) = make_float4(xb[8],xb[9],0.f,0.f);
        *(float4*)(dd+8) = make_float4(dv[8],dv[9],0.f,0.f);
    }
}

// ============ fused layer, WPT lanes/node, packed-u gather ============
template<int LAST>
__global__ __launch_bounds__(256) void k_layer(const ent12* __restrict__ entries,
    const int* __restrict__ start, const int* __restrict__ cnt,
    const float* __restrict__ W1, const float* __restrict__ W2,
    const float* __restrict__ x_, const float* __restrict__ dinv,
    const unsigned* __restrict__ uin,
    const float* __restrict__ lin, const float* __restrict__ gw_next,
    const float* __restrict__ gb, const float* __restrict__ oW,
    unsigned* __restrict__ uout, float* __restrict__ out)
{
    __shared__ float sW1[4*H], sW2[H*H], slin[2*H*H], sgw[H], sgb[H], soW[4*H];
    int tid = threadIdx.x;
    for (int k = tid; k < 4*H; k += 256) sW1[k] = W1[k];
    for (int k = tid; k < H*H; k += 256) sW2[k] = W2[k];
    for (int k = tid; k < 2*H*H; k += 256) slin[k] = lin[k];
    if (tid < H) sgb[tid] = gb[tid];
    if (LAST) { if (tid < 4*H) soW[tid] = oW[tid]; }
    else      { if (tid >= 64 && tid < 64+H) sgw[tid-64] = gw_next[tid-64]; }
    __syncthreads();
    int node = blockIdx.x * (256 / WPT) + (tid >> 2);
    int r = tid & (WPT - 1);
    if (node >= N_NODES) return;
    int st = start[node], n = cnt[node];
    float s[H];
    #pragma unroll
    for (int ch = 0; ch < H; ++ch) s[ch] = 0.f;
    for (int e = st + r; e < st + n; e += WPT) {
        ent12 ent = entries[e];
        float ew[H];
        ew_from_packed(ent.a, ent.b, sW1, sW2, ew);
        const unsigned* up = uin + (size_t)(ent.w & ROWM) * SU;
        uint4 w = *(const uint4*)up;
        unsigned w2 = up[4];
        float ur[H];
        ur[0]=bflo(w.x); ur[1]=bfhi(w.x);
        ur[2]=bflo(w.y); ur[3]=bfhi(w.y);
        ur[4]=bflo(w.z); ur[5]=bfhi(w.z);
        ur[6]=bflo(w.w); ur[7]=bfhi(w.w);
        ur[8]=bflo(w2);  ur[9]=bfhi(w2);
        #pragma unroll
        for (int ch = 0; ch < H; ++ch) s[ch] = fmaf(ew[ch], ur[ch], s[ch]);
    }
    #pragma unroll
    for (int ch = 0; ch < H; ++ch) {
        s[ch] += __shfl_xor(s[ch], 1);
        s[ch] += __shfl_xor(s[ch], 2);
    }
    const float* xi = x_   + (size_t)node * S;
    const float* di = dinv + (size_t)node * S;
    const unsigned* us = uin + (size_t)node * SU;
    uint4 wv = *(const uint4*)us;
    unsigned wv2 = us[4];
    float ui[H];
    ui[0]=bflo(wv.x); ui[1]=bfhi(wv.x);
    ui[2]=bflo(wv.y); ui[3]=bfhi(wv.y);
    ui[4]=bflo(wv.z); ui[5]=bfhi(wv.z);
    ui[6]=bflo(wv.w); ui[7]=bfhi(wv.w);
    ui[8]=bflo(wv2);  ui[9]=bfhi(wv2);
    float xv[H], agg[H];
    #pragma unroll
    for (int ch = 0; ch < H; ++ch) {
        xv[ch] = xi[ch];
        agg[ch] = di[ch] * (s[ch] + ui[ch]) + sgb[ch];  // self-loop folded in
    }
    float h[H];
    #pragma unroll
    for (int j = 0; j < H; ++j) {
        float a = xv[j];                                 // residual
        #pragma unroll
        for (int k = 0; k < H; ++k) a = fmaf(xv[k], slin[k*H + j], a);
        #pragma unroll
        for (int k = 0; k < H; ++k) a = fmaf(agg[k], slin[(H+k)*H + j], a);
        h[j] = a;
    }
    if (!LAST) {
        float un[H];
        #pragma unroll
        for (int ch = 0; ch < H; ++ch)
            un[ch] = di[ch] * fmaxf(h[ch], 0.f) * sgw[ch];
        unsigned* ud = uout + (size_t)node * SU;
        if (r == 0)
            *(uint4*)ud = make_uint4(pack2bf(un[0],un[1]), pack2bf(un[2],un[3]),
                                     pack2bf(un[4],un[5]), pack2bf(un[6],un[7]));
        else if (r == 1)
            ud[4] = pack2bf(un[8], un[9]);
    } else {
        float z0 = 0.f, z1 = 0.f;
        #pragma unroll
        for (int k = 0; k < H; ++k) { z0 = fmaf(xv[k], soW[2*k],   z0);
                                      z1 = fmaf(xv[k], soW[2*k+1], z1); }
        #pragma unroll
        for (int k = 0; k < H; ++k) { float hr = fmaxf(h[k], 0.f);
                                      z0 = fmaf(hr, soW[2*(H+k)],   z0);
                                      z1 = fmaf(hr, soW[2*(H+k)+1], z1); }
        if (r == 0) out[node] = 1.0f / (1.0f + expf(z0 - z1));
    }
}

extern "C" void kernel_launch(void* const* d_in, const int* in_sizes, int n_in,
                              void* d_out, int out_size, void* d_ws, size_t ws_size,
                              hipStream_t stream)
{
    const float* x     = (const float*)d_in[0];
    const int*   ei    = (const int*)  d_in[1];
    const float* attr  = (const float*)d_in[2];
    const float* ew_W1 = (const float*)d_in[3];
    const float* ew_W2 = (const float*)d_in[4];
    const float* iW    = (const float*)d_in[5];
    const float* ib    = (const float*)d_in[6];
    const float* gcn_w = (const float*)d_in[7];
    const float* gcn_b = (const float*)d_in[8];
    const float* lin_W = (const float*)d_in[9];
    const float* oW    = (const float*)d_in[10];
    float* out = (float*)d_out;
    char* ws = (char*)d_ws;

    size_t o = 0;
    ent12* stage   = (ent12*)(ws + o); o += (size_t)NBKT * BCAP * 12;      // 43.2 MB
    ent12* entries = (ent12*)(ws + o); o += (size_t)NBKT * BCAP * 12;      // 43.2 MB
    float* x_   = (float*)(ws + o); o += (size_t)N_NODES * S * 4;          // 4.8 MB
    float* dinv = (float*)(ws + o); o += (size_t)N_NODES * S * 4;          // 4.8 MB
    unsigned* u_a = (unsigned*)(ws + o); o += (size_t)N_NODES * SU * 4;    // 3.2 MB
    unsigned* u_b = (unsigned*)(ws + o); o += (size_t)N_NODES * SU * 4;    // 3.2 MB
    int* cnt    = (int*)(ws + o); o += (size_t)N_NODES * 4;
    int* start  = (int*)(ws + o); o += (size_t)N_NODES * 4;
    int* bptr   = (int*)(ws + o); o += (size_t)NBKT * 4;

    dim3 blk(256);
    dim3 ggrid((N_NODES * WPT + 255) / 256);   // 1563 blocks, 64 nodes each

    k_binit<<<(NBKT + 255) / 256, blk, 0, stream>>>(bptr);
    k_fill1<<<NFB, NT1, 0, stream>>>(ei, attr, bptr, stage);
    k_fill2<<<NBKT, NT2, 0, stream>>>(stage, bptr, entries, start, cnt);

    k_deg  <<<ggrid, blk, 0, stream>>>(entries, start, cnt, ew_W1, ew_W2,
                                       x, iW, ib, gcn_w, x_, dinv, u_a);
    // layer 0: reads u_a, writes u_b
    k_layer<0><<<ggrid, blk, 0, stream>>>(entries, start, cnt, ew_W1, ew_W2,
        x_, dinv, u_a, lin_W + 0*2*H*H, gcn_w + 1*H, gcn_b + 0*H, oW, u_b, out);
    // layer 1: reads u_b, writes u_a
    k_layer<0><<<ggrid, blk, 0, stream>>>(entries, start, cnt, ew_W1, ew_W2,
        x_, dinv, u_b, lin_W + 1*2*H*H, gcn_w + 2*H, gcn_b + 1*H, oW, u_a, out);
    // layer 2: reads u_a, writes out
    k_layer<1><<<ggrid, blk, 0, stream>>>(entries, start, cnt, ew_W1, ew_W2,
        x_, dinv, u_a, lin_W + 2*2*H*H, nullptr, gcn_b + 2*H, oW, nullptr, out);
}

// Round 23
// 263.190 us; speedup vs baseline: 1.1498x; 1.0352x over previous
//
#include <hip/hip_runtime.h>
#include <math.h>

#define N_NODES 100000
#define N_EDGES 3200000
#define H 10
#define S 12          // f32 node-table stride (48B)
#define SU 8          // packed-u stride in uints (32B)
#define IN_DIM 16
#define WPT 4         // lanes per node in gather passes
#define NB 128        // nodes per bucket
#define NBKT 782      // ceil(N_NODES / NB)
#define BCAP 4608     // capacity/bucket (mean 4092, +8 sigma)
#define FTILE 4096    // edges per fill block (4 per thread @1024)
#define NFB 782       // ceil(N_EDGES / FTILE)
#define NT1 1024      // fill1 threads
#define NT2 512       // fill2 threads
#define ROWM 0x1FFFFu

struct ent12 { unsigned a, b, w; };       // {bf16(a0,a1), bf16(a2,a3), row | cl<<17}
struct ent24 { unsigned e01,e23,e45,e67,e89,row; };  // precomputed bf16 ew + row

// ============ bptr init ============
__global__ __launch_bounds__(256) void k_binit(int* __restrict__ bptr)
{
    int i = blockIdx.x * 256 + threadIdx.x;
    if (i < NBKT) bptr[i] = i * BCAP;
}

// ---- bf16 pack (round-to-nearest-even) / unpack ----
__device__ __forceinline__ unsigned pack2bf(float a, float b)
{
    unsigned ua = __float_as_uint(a), ub = __float_as_uint(b);
    unsigned ra = (ua + 0x7FFFu + ((ua >> 16) & 1u)) >> 16;
    unsigned rb = (ub + 0x7FFFu + ((ub >> 16) & 1u)) >> 16;
    return ra | (rb << 16);
}
__device__ __forceinline__ float bflo(unsigned v) { return __uint_as_float(v << 16); }
__device__ __forceinline__ float bfhi(unsigned v) { return __uint_as_float(v & 0xffff0000u); }

// ============ fill phase 1: LDS-sorted tile scatter -> BURST writes (12B recs) ============
__global__ __launch_bounds__(NT1) void k_fill1(const int* __restrict__ ei,
    const float* __restrict__ attr, int* __restrict__ bptr,
    ent12* __restrict__ stage)
{
    __shared__ int lcnt[NBKT];
    __shared__ int lbase[NBKT];
    __shared__ int lscan[NBKT];
    __shared__ int sscan[2][NT1];
    __shared__ unsigned sa[FTILE], sb[FTILE], srw[FTILE];
    __shared__ unsigned short sbkt[FTILE];
    int tid = threadIdx.x;
    int base = blockIdx.x * FTILE;
    for (int k = tid; k < NBKT; k += NT1) lcnt[k] = 0;
    __syncthreads();
    // phase A: histogram
    int c[FTILE / NT1];
    #pragma unroll
    for (int k = 0; k < FTILE / NT1; ++k) {
        int e = base + k * NT1 + tid;
        c[k] = (e < N_EDGES) ? ei[N_EDGES + e] : -1;
        if (c[k] >= 0) atomicAdd(&lcnt[c[k] >> 7], 1);
    }
    __syncthreads();
    // phase B: exclusive scan of bucket counts (2 buckets/thread)
    int b0 = 2 * tid, b1 = 2 * tid + 1;
    int v0 = (b0 < NBKT) ? lcnt[b0] : 0;
    int v1 = (b1 < NBKT) ? lcnt[b1] : 0;
    int psum = v0 + v1;
    sscan[0][tid] = psum;
    __syncthreads();
    int cur = 0;
    for (int off = 1; off < NT1; off <<= 1) {
        int t = (tid >= off) ? sscan[cur][tid - off] : 0;
        int xx = sscan[cur][tid] + t;
        sscan[cur ^ 1][tid] = xx;
        cur ^= 1;
        __syncthreads();
    }
    int ep = sscan[cur][tid] - psum;
    if (b0 < NBKT) lscan[b0] = ep;
    if (b1 < NBKT) lscan[b1] = ep + v0;
    __syncthreads();
    // phase C: reserve global runs (exact size) + reset counters
    for (int k = tid; k < NBKT; k += NT1) {
        int n = lcnt[k];
        lbase[k] = n ? atomicAdd(&bptr[k], n) : 0;
        lcnt[k] = 0;
    }
    __syncthreads();
    // phase D: stage into LDS ordered by bucket
    #pragma unroll
    for (int k = 0; k < FTILE / NT1; ++k) {
        if (c[k] < 0) continue;
        int e = base + k * NT1 + tid;
        int b = c[k] >> 7;
        int slot = atomicAdd(&lcnt[b], 1);
        int pos = lscan[b] + slot;
        float4 a = ((const float4*)attr)[e];
        sa[pos] = pack2bf(a.x, a.y);
        sb[pos] = pack2bf(a.z, a.w);
        srw[pos] = (unsigned)ei[e] | ((unsigned)(c[k] & (NB - 1)) << 17);
        sbkt[pos] = (unsigned short)b;
    }
    __syncthreads();
    // phase E: burst write — consecutive threads -> consecutive global dests
    int total = min(FTILE, N_EDGES - base);
    for (int i = tid; i < total; i += NT1) {
        int b = (int)sbkt[i];
        int dest = i - lscan[b] + lbase[b];
        if (dest < (b + 1) * BCAP) {
            ent12 v;
            v.a = sa[i];
            v.b = sb[i];
            v.w = srw[i];
            stage[dest] = v;
        }
    }
}

// ============ shared helper: ew from packed attr ============
__device__ __forceinline__ void ew_from_packed(unsigned px, unsigned py,
    const float* sW1, const float* sW2, float ew[H])
{
    float ax = bflo(px), ay = bfhi(px);
    float az = bflo(py), aw = bfhi(py);
    float tt[H];
    #pragma unroll
    for (int j = 0; j < H; ++j)
        tt[j] = fmaxf(fmaf(ax, sW1[j], fmaf(ay, sW1[H+j],
                      fmaf(az, sW1[2*H+j], aw*sW1[3*H+j]))), 0.f);
    #pragma unroll
    for (int ch = 0; ch < H; ++ch) {
        float v = 0.f;
        #pragma unroll
        for (int j = 0; j < H; ++j) v = fmaf(tt[j], sW2[j*H + ch], v);
        ew[ch] = fmaxf(v, 0.f);
    }
}

// ============ fill phase 2: reorder + COMPUTE EW ONCE -> 24B entries ============
__global__ __launch_bounds__(NT2) void k_fill2(const ent12* __restrict__ stage,
    const int* __restrict__ bptr,
    const float* __restrict__ W1, const float* __restrict__ W2,
    ent24* __restrict__ entries, int* __restrict__ start, int* __restrict__ cnt)
{
    __shared__ float sW1[4*H], sW2[H*H];
    __shared__ int hist[NB];
    __shared__ int buf[2][NB];
    __shared__ int cur[NB];
    int tid = threadIdx.x;
    int b = blockIdx.x;
    if (tid < 4*H) sW1[tid] = W1[tid];
    if (tid >= 64 && tid < 64 + H*H) sW2[tid-64] = W2[tid-64];
    if (tid < NB) hist[tid] = 0;
    __syncthreads();
    int st = b * BCAP;
    int en = min(bptr[b], st + BCAP);
    for (int e = st + tid; e < en; e += NT2)
        atomicAdd(&hist[stage[e].w >> 17], 1);
    __syncthreads();
    if (tid < NB) buf[0][tid] = hist[tid];
    __syncthreads();
    int cs = 0;
    for (int off = 1; off < NB; off <<= 1) {
        if (tid < NB) {
            int t = (tid >= off) ? buf[cs][tid - off] : 0;
            buf[cs ^ 1][tid] = buf[cs][tid] + t;
        }
        cs ^= 1;
        __syncthreads();
    }
    if (tid < NB) {
        int ex = buf[cs][tid] - hist[tid];            // exclusive prefix
        cur[tid] = ex;
        int node = b * NB + tid;
        if (node < N_NODES) {
            start[node] = st + ex;
            cnt[node]   = hist[tid];
        }
    }
    __syncthreads();
    for (int e = st + tid; e < en; e += NT2) {
        ent12 ent = stage[e];
        int cl = (int)(ent.w >> 17);
        float ew[H];
        ew_from_packed(ent.a, ent.b, sW1, sW2, ew);
        ent24 v;
        v.e01 = pack2bf(ew[0], ew[1]);
        v.e23 = pack2bf(ew[2], ew[3]);
        v.e45 = pack2bf(ew[4], ew[5]);
        v.e67 = pack2bf(ew[6], ew[7]);
        v.e89 = pack2bf(ew[8], ew[9]);
        v.row = ent.w & ROWM;
        int slot = st + atomicAdd(&cur[cl], 1);
        entries[slot] = v;                            // confined window
    }
}

// ---- unpack 10 bf16 ew from ent24 ----
__device__ __forceinline__ void ew_unpack(const ent24& v, float ew[H])
{
    ew[0]=bflo(v.e01); ew[1]=bfhi(v.e01);
    ew[2]=bflo(v.e23); ew[3]=bfhi(v.e23);
    ew[4]=bflo(v.e45); ew[5]=bfhi(v.e45);
    ew[6]=bflo(v.e67); ew[7]=bfhi(v.e67);
    ew[8]=bflo(v.e89); ew[9]=bfhi(v.e89);
}

// ============ deg pass (fused node init), WPT lanes/node ============
__global__ __launch_bounds__(256) void k_deg(const ent24* __restrict__ entries,
    const int* __restrict__ start, const int* __restrict__ cnt,
    const float* __restrict__ x, const float* __restrict__ iW,
    const float* __restrict__ ib, const float* __restrict__ gw0,
    float* __restrict__ x_, float* __restrict__ dinv, unsigned* __restrict__ u)
{
    __shared__ float siW[IN_DIM*H], sib[H], sgw[H];
    int tid = threadIdx.x;
    for (int k = tid; k < IN_DIM*H; k += 256) siW[k] = iW[k];
    if (tid < H) sib[tid] = ib[tid];
    if (tid >= 32 && tid < 32+H) sgw[tid-32] = gw0[tid-32];
    __syncthreads();
    int node = blockIdx.x * (256 / WPT) + (tid >> 2);
    int r = tid & (WPT - 1);
    if (node >= N_NODES) return;
    int st = start[node], n = cnt[node];
    float s[H];
    #pragma unroll
    for (int ch = 0; ch < H; ++ch) s[ch] = 0.f;
    for (int e = st + r; e < st + n; e += WPT) {
        ent24 ent = entries[e];
        float ew[H];
        ew_unpack(ent, ew);
        #pragma unroll
        for (int ch = 0; ch < H; ++ch) s[ch] += ew[ch];
    }
    #pragma unroll
    for (int ch = 0; ch < H; ++ch) {
        s[ch] += __shfl_xor(s[ch], 1);
        s[ch] += __shfl_xor(s[ch], 2);
    }
    const float4* xv = (const float4*)(x + (size_t)node * IN_DIM);
    float xi[IN_DIM];
    float4 a0 = xv[0], a1 = xv[1], a2 = xv[2], a3 = xv[3];
    xi[0]=a0.x; xi[1]=a0.y; xi[2]=a0.z; xi[3]=a0.w;
    xi[4]=a1.x; xi[5]=a1.y; xi[6]=a1.z; xi[7]=a1.w;
    xi[8]=a2.x; xi[9]=a2.y; xi[10]=a2.z; xi[11]=a2.w;
    xi[12]=a3.x; xi[13]=a3.y; xi[14]=a3.z; xi[15]=a3.w;
    float xb[H], dv[H], uu[H];
    #pragma unroll
    for (int j = 0; j < H; ++j) {
        float a = sib[j];
        #pragma unroll
        for (int k = 0; k < IN_DIM; ++k) a = fmaf(xi[k], siW[k*H + j], a);
        xb[j] = a;
    }
    #pragma unroll
    for (int ch = 0; ch < H; ++ch) {
        float di = rsqrtf(1.0f + s[ch]);   // deg >= 1 (self loop)
        dv[ch] = di;
        uu[ch] = di * fmaxf(xb[ch], 0.f) * sgw[ch];
    }
    float* xd = x_   + (size_t)node * S;
    float* dd = dinv + (size_t)node * S;
    unsigned* ud = u + (size_t)node * SU;
    if (r == 0) {
        *(float4*)(xd+0) = make_float4(xb[0],xb[1],xb[2],xb[3]);
        *(float4*)(dd+0) = make_float4(dv[0],dv[1],dv[2],dv[3]);
        *(uint4*)(ud)    = make_uint4(pack2bf(uu[0],uu[1]), pack2bf(uu[2],uu[3]),
                                      pack2bf(uu[4],uu[5]), pack2bf(uu[6],uu[7]));
    } else if (r == 1) {
        *(float4*)(xd+4) = make_float4(xb[4],xb[5],xb[6],xb[7]);
        *(float4*)(dd+4) = make_float4(dv[4],dv[5],dv[6],dv[7]);
        ud[4] = pack2bf(uu[8], uu[9]);
    } else if (r == 2) {
        *(float4*)(xd+8) = make_float4(xb[8],xb[9],0.f,0.f);
        *(float4*)(dd+8) = make_float4(dv[8],dv[9],0.f,0.f);
    }
}

// ============ fused layer, WPT lanes/node, precomputed-ew gather ============
template<int LAST>
__global__ __launch_bounds__(256) void k_layer(const ent24* __restrict__ entries,
    const int* __restrict__ start, const int* __restrict__ cnt,
    const float* __restrict__ x_, const float* __restrict__ dinv,
    const unsigned* __restrict__ uin,
    const float* __restrict__ lin, const float* __restrict__ gw_next,
    const float* __restrict__ gb, const float* __restrict__ oW,
    unsigned* __restrict__ uout, float* __restrict__ out)
{
    __shared__ float slin[2*H*H], sgw[H], sgb[H], soW[4*H];
    int tid = threadIdx.x;
    for (int k = tid; k < 2*H*H; k += 256) slin[k] = lin[k];
    if (tid < H) sgb[tid] = gb[tid];
    if (LAST) { if (tid >= 32 && tid < 32+4*H) soW[tid-32] = oW[tid-32]; }
    else      { if (tid >= 32 && tid < 32+H)   sgw[tid-32] = gw_next[tid-32]; }
    __syncthreads();
    int node = blockIdx.x * (256 / WPT) + (tid >> 2);
    int r = tid & (WPT - 1);
    if (node >= N_NODES) return;
    int st = start[node], n = cnt[node];
    float s[H];
    #pragma unroll
    for (int ch = 0; ch < H; ++ch) s[ch] = 0.f;
    for (int e = st + r; e < st + n; e += WPT) {
        ent24 ent = entries[e];
        float ew[H];
        ew_unpack(ent, ew);
        const unsigned* up = uin + (size_t)ent.row * SU;
        uint4 w = *(const uint4*)up;
        unsigned w2 = up[4];
        float ur[H];
        ur[0]=bflo(w.x); ur[1]=bfhi(w.x);
        ur[2]=bflo(w.y); ur[3]=bfhi(w.y);
        ur[4]=bflo(w.z); ur[5]=bfhi(w.z);
        ur[6]=bflo(w.w); ur[7]=bfhi(w.w);
        ur[8]=bflo(w2);  ur[9]=bfhi(w2);
        #pragma unroll
        for (int ch = 0; ch < H; ++ch) s[ch] = fmaf(ew[ch], ur[ch], s[ch]);
    }
    #pragma unroll
    for (int ch = 0; ch < H; ++ch) {
        s[ch] += __shfl_xor(s[ch], 1);
        s[ch] += __shfl_xor(s[ch], 2);
    }
    const float* xi = x_   + (size_t)node * S;
    const float* di = dinv + (size_t)node * S;
    const unsigned* us = uin + (size_t)node * SU;
    uint4 wv = *(const uint4*)us;
    unsigned wv2 = us[4];
    float ui[H];
    ui[0]=bflo(wv.x); ui[1]=bfhi(wv.x);
    ui[2]=bflo(wv.y); ui[3]=bfhi(wv.y);
    ui[4]=bflo(wv.z); ui[5]=bfhi(wv.z);
    ui[6]=bflo(wv.w); ui[7]=bfhi(wv.w);
    ui[8]=bflo(wv2);  ui[9]=bfhi(wv2);
    float xv[H], agg[H];
    #pragma unroll
    for (int ch = 0; ch < H; ++ch) {
        xv[ch] = xi[ch];
        agg[ch] = di[ch] * (s[ch] + ui[ch]) + sgb[ch];  // self-loop folded in
    }
    float h[H];
    #pragma unroll
    for (int j = 0; j < H; ++j) {
        float a = xv[j];                                 // residual
        #pragma unroll
        for (int k = 0; k < H; ++k) a = fmaf(xv[k], slin[k*H + j], a);
        #pragma unroll
        for (int k = 0; k < H; ++k) a = fmaf(agg[k], slin[(H+k)*H + j], a);
        h[j] = a;
    }
    if (!LAST) {
        float un[H];
        #pragma unroll
        for (int ch = 0; ch < H; ++ch)
            un[ch] = di[ch] * fmaxf(h[ch], 0.f) * sgw[ch];
        unsigned* ud = uout + (size_t)node * SU;
        if (r == 0)
            *(uint4*)ud = make_uint4(pack2bf(un[0],un[1]), pack2bf(un[2],un[3]),
                                     pack2bf(un[4],un[5]), pack2bf(un[6],un[7]));
        else if (r == 1)
            ud[4] = pack2bf(un[8], un[9]);
    } else {
        float z0 = 0.f, z1 = 0.f;
        #pragma unroll
        for (int k = 0; k < H; ++k) { z0 = fmaf(xv[k], soW[2*k],   z0);
                                      z1 = fmaf(xv[k], soW[2*k+1], z1); }
        #pragma unroll
        for (int k = 0; k < H; ++k) { float hr = fmaxf(h[k], 0.f);
                                      z0 = fmaf(hr, soW[2*(H+k)],   z0);
                                      z1 = fmaf(hr, soW[2*(H+k)+1], z1); }
        if (r == 0) out[node] = 1.0f / (1.0f + expf(z0 - z1));
    }
}

extern "C" void kernel_launch(void* const* d_in, const int* in_sizes, int n_in,
                              void* d_out, int out_size, void* d_ws, size_t ws_size,
                              hipStream_t stream)
{
    const float* x     = (const float*)d_in[0];
    const int*   ei    = (const int*)  d_in[1];
    const float* attr  = (const float*)d_in[2];
    const float* ew_W1 = (const float*)d_in[3];
    const float* ew_W2 = (const float*)d_in[4];
    const float* iW    = (const float*)d_in[5];
    const float* ib    = (const float*)d_in[6];
    const float* gcn_w = (const float*)d_in[7];
    const float* gcn_b = (const float*)d_in[8];
    const float* lin_W = (const float*)d_in[9];
    const float* oW    = (const float*)d_in[10];
    float* out = (float*)d_out;
    char* ws = (char*)d_ws;

    size_t o = 0;
    ent12* stage   = (ent12*)(ws + o); o += (size_t)NBKT * BCAP * 12;      // 43.2 MB
    ent24* entries = (ent24*)(ws + o); o += (size_t)NBKT * BCAP * 24;      // 86.5 MB
    float* x_   = (float*)(ws + o); o += (size_t)N_NODES * S * 4;          // 4.8 MB
    float* dinv = (float*)(ws + o); o += (size_t)N_NODES * S * 4;          // 4.8 MB
    unsigned* u_a = (unsigned*)(ws + o); o += (size_t)N_NODES * SU * 4;    // 3.2 MB
    unsigned* u_b = (unsigned*)(ws + o); o += (size_t)N_NODES * SU * 4;    // 3.2 MB
    int* cnt    = (int*)(ws + o); o += (size_t)N_NODES * 4;
    int* start  = (int*)(ws + o); o += (size_t)N_NODES * 4;
    int* bptr   = (int*)(ws + o); o += (size_t)NBKT * 4;

    dim3 blk(256);
    dim3 ggrid((N_NODES * WPT + 255) / 256);   // 1563 blocks, 64 nodes each

    k_binit<<<(NBKT + 255) / 256, blk, 0, stream>>>(bptr);
    k_fill1<<<NFB, NT1, 0, stream>>>(ei, attr, bptr, stage);
    k_fill2<<<NBKT, NT2, 0, stream>>>(stage, bptr, ew_W1, ew_W2, entries, start, cnt);

    k_deg  <<<ggrid, blk, 0, stream>>>(entries, start, cnt,
                                       x, iW, ib, gcn_w, x_, dinv, u_a);
    // layer 0: reads u_a, writes u_b
    k_layer<0><<<ggrid, blk, 0, stream>>>(entries, start, cnt,
        x_, dinv, u_a, lin_W + 0*2*H*H, gcn_w + 1*H, gcn_b + 0*H, oW, u_b, out);
    // layer 1: reads u_b, writes u_a
    k_layer<0><<<ggrid, blk, 0, stream>>>(entries, start, cnt,
        x_, dinv, u_b, lin_W + 1*2*H*H, gcn_w + 2*H, gcn_b + 1*H, oW, u_a, out);
    // layer 2: reads u_a, writes out
    k_layer<1><<<ggrid, blk, 0, stream>>>(entries, start, cnt,
        x_, dinv, u_a, lin_W + 2*2*H*H, nullptr, gcn_b + 2*H, oW, nullptr, out);
}